// Round 1
// baseline (70.635 us; speedup 1.0000x reference)
//
#include <hip/hip_runtime.h>
#include <cmath>

// NALU forward: B=8192, D=U=128.
// out = g1*a1 + (1-g1)*parity*exp(min(mlog,20)+slog)
//   a1   = x @ w1
//   mlog = log(max(|x|,1e-7)) @ w2
//   slog = (x<0) @ log|1-2*|w2^T||   (sign path in log space)
//   cnt  = (x<0) @ [1-2*|w2^T| < 0]  (parity of negative factors)
// clip(ms,-1,1) is a no-op since slog <= 0 always.

typedef __bf16  bf16x8 __attribute__((ext_vector_type(8)));
typedef float   f32x4  __attribute__((ext_vector_type(4)));

#define NROWS 8192
#define KDIM  128
#define UDIM  128

__device__ __forceinline__ unsigned short f2bf(float f) {
    union { float f; unsigned int u; } v; v.f = f;
    unsigned int u = v.u;
    // round-to-nearest-even bf16
    unsigned int r = (u + 0x7FFFu + ((u >> 16) & 1u)) >> 16;
    return (unsigned short)r;
}

__device__ __forceinline__ unsigned int pck(unsigned short a, unsigned short b) {
    return (unsigned int)a | ((unsigned int)b << 16);
}

__device__ __forceinline__ float sigmoidf_(float v) {
    return 1.0f / (1.0f + expf(-v));
}

// ---------------------------------------------------------------------------
// Prep: compute the 4 derived weight matrices in bf16, stored in exact MFMA
// B-fragment order: Bsw[mat][nblk(8)][kstep(4)][lane(64)][j(8)]
//   lane = quad*16 + (n&15), quad=(k>>3)&3 ; value = Bmat[k][n]
// mat 0: w1[k][n]            = tanh(w_hat[k,n])*sig(m_hat[k,n])
// mat 1: w2[k][n]            = tanh(whp[k,n])*sig(mhp[k,n])
// mat 2: S[k][n]             = max(log|1-2*|w2[n,k]||, -80)
// mat 3: neg[k][n]           = (1-2*|w2[n,k]|) < 0 ? 1 : 0
// ---------------------------------------------------------------------------
__global__ void nalu_prep(const float* __restrict__ w_hat,
                          const float* __restrict__ m_hat,
                          const float* __restrict__ whp,
                          const float* __restrict__ mhp,
                          unsigned short* __restrict__ Bsw) {
    int i = blockIdx.x * 256 + threadIdx.x;   // 0..16383
    int n = i >> 7;      // output column u
    int k = i & 127;     // reduction index d
    int dk = k * 128 + n;   // (d=k, u=n) row-major [D,U]
    int ud = n * 128 + k;   // (row=n, col=k) for the transposed sign path

    float w1v = tanhf(w_hat[dk]) * sigmoidf_(m_hat[dk]);
    float w2v = tanhf(whp[dk])   * sigmoidf_(mhp[dk]);
    float a   = fabsf(tanhf(whp[ud]) * sigmoidf_(mhp[ud]));
    float f   = 1.0f - 2.0f * a;
    float Sv  = fmaxf(logf(fmaxf(fabsf(f), 1e-38f)), -80.0f);
    float ngv = (f < 0.0f) ? 1.0f : 0.0f;

    int nblk = n >> 4, l16 = n & 15, kstep = k >> 5, quad = (k >> 3) & 3, j = k & 7;
    int lane = quad * 16 + l16;
    int base = ((nblk * 4 + kstep) * 64 + lane) * 8 + j;   // mat-0 offset
    const int MATSTRIDE = 8 * 4 * 64 * 8;                  // 16384 elements

    Bsw[base]                 = f2bf(w1v);
    Bsw[base + MATSTRIDE]     = f2bf(w2v);
    Bsw[base + 2 * MATSTRIDE] = f2bf(Sv);
    Bsw[base + 3 * MATSTRIDE] = f2bf(ngv);
}

// ---------------------------------------------------------------------------
// Main: 256 blocks x 256 threads. Block = 32 rows x 128 cols.
// Wave w: rows [blk*32, +32) (2 msub of 16), cols [w*32, +32) (2 nsub of 16).
// A staged in LDS as [mat][m 32][k 136] bf16 (pad keeps 16B align, 2-way banks).
// ---------------------------------------------------------------------------
__global__ __launch_bounds__(256, 1)
void nalu_main(const float* __restrict__ x,
               const unsigned short* __restrict__ Bsw,
               const float* __restrict__ g,
               float* __restrict__ out) {
    __shared__ __align__(16) unsigned short As[3][32][136];

    const int t    = threadIdx.x;
    const int wave = t >> 6;
    const int lane = t & 63;
    const int quad = lane >> 4;
    const int l16  = lane & 15;
    const int rowblk = blockIdx.x * 32;

    // --- Issue all B-fragment loads up front (coalesced dwordx4, L2-hot) ---
    bf16x8 Bf[4][2][4];   // [mat][nsub][kstep]
    const bf16x8* Bp = reinterpret_cast<const bf16x8*>(Bsw);
    #pragma unroll
    for (int mat = 0; mat < 4; ++mat)
        #pragma unroll
        for (int ns = 0; ns < 2; ++ns)
            #pragma unroll
            for (int ks = 0; ks < 4; ++ks) {
                int nblk = wave * 2 + ns;
                Bf[mat][ns][ks] = Bp[((mat * 8 + nblk) * 4 + ks) * 64 + lane];
            }

    // --- Stage A matrices (x, log|x|, x<0) into LDS as bf16 ---
    const float4* xv = reinterpret_cast<const float4*>(x + rowblk * 128);
    #pragma unroll
    for (int it = 0; it < 4; ++it) {
        int idx  = t + it * 256;      // 0..1023 = 32 rows x 32 float4
        int row  = idx >> 5;
        int col4 = idx & 31;
        float4 v = xv[idx];
        float vv[4] = {v.x, v.y, v.z, v.w};
        unsigned short sx[4], sl[4], sn[4];
        #pragma unroll
        for (int j = 0; j < 4; ++j) {
            float f = vv[j];
            sx[j] = f2bf(f);
            sl[j] = f2bf(logf(fmaxf(fabsf(f), 1e-7f)));
            sn[j] = (f < 0.0f) ? 0x3F80u : 0u;   // bf16 1.0 / 0.0
        }
        uint2 px = {pck(sx[0], sx[1]), pck(sx[2], sx[3])};
        uint2 pl = {pck(sl[0], sl[1]), pck(sl[2], sl[3])};
        uint2 pn = {pck(sn[0], sn[1]), pck(sn[2], sn[3])};
        *reinterpret_cast<uint2*>(&As[0][row][col4 * 4]) = px;
        *reinterpret_cast<uint2*>(&As[1][row][col4 * 4]) = pl;
        *reinterpret_cast<uint2*>(&As[2][row][col4 * 4]) = pn;
    }
    __syncthreads();

    // --- Accumulators: 4 chains x 2 msub x 2 nsub ---
    f32x4 accA[2][2], accM[2][2], accS[2][2], accC[2][2];
    #pragma unroll
    for (int ms = 0; ms < 2; ++ms)
        #pragma unroll
        for (int ns = 0; ns < 2; ++ns) {
            f32x4 z = {0.0f, 0.0f, 0.0f, 0.0f};
            accA[ms][ns] = z; accM[ms][ns] = z; accS[ms][ns] = z; accC[ms][ns] = z;
        }

    // --- K loop: 4 ksteps of 32, fully unrolled ---
    #pragma unroll
    for (int ks = 0; ks < 4; ++ks) {
        bf16x8 Ax[2], Al[2], An[2];
        #pragma unroll
        for (int ms = 0; ms < 2; ++ms) {
            int m = ms * 16 + l16;
            int k = ks * 32 + quad * 8;
            Ax[ms] = *reinterpret_cast<const bf16x8*>(&As[0][m][k]);
            Al[ms] = *reinterpret_cast<const bf16x8*>(&As[1][m][k]);
            An[ms] = *reinterpret_cast<const bf16x8*>(&As[2][m][k]);
        }
        #pragma unroll
        for (int ms = 0; ms < 2; ++ms)
            #pragma unroll
            for (int ns = 0; ns < 2; ++ns) {
                accA[ms][ns] = __builtin_amdgcn_mfma_f32_16x16x32_bf16(Ax[ms], Bf[0][ns][ks], accA[ms][ns], 0, 0, 0);
                accM[ms][ns] = __builtin_amdgcn_mfma_f32_16x16x32_bf16(Al[ms], Bf[1][ns][ks], accM[ms][ns], 0, 0, 0);
                accS[ms][ns] = __builtin_amdgcn_mfma_f32_16x16x32_bf16(An[ms], Bf[2][ns][ks], accS[ms][ns], 0, 0, 0);
                accC[ms][ns] = __builtin_amdgcn_mfma_f32_16x16x32_bf16(An[ms], Bf[3][ns][ks], accC[ms][ns], 0, 0, 0);
            }
    }

    // --- Epilogue: C/D layout col=lane&15, row=quad*4+reg ---
    #pragma unroll
    for (int ns = 0; ns < 2; ++ns) {
        int u = wave * 32 + ns * 16 + l16;
        float g1 = sigmoidf_(g[u]);
        float om = 1.0f - g1;
        #pragma unroll
        for (int ms = 0; ms < 2; ++ms) {
            int rbase = rowblk + ms * 16 + quad * 4;
            #pragma unroll
            for (int r = 0; r < 4; ++r) {
                float a1 = accA[ms][ns][r];
                float ml = accM[ms][ns][r];
                float sl = accS[ms][ns][r];
                float cn = accC[ms][ns][r];   // exact integer count
                float par = 1.0f - 2.0f * (cn - 2.0f * floorf(cn * 0.5f));
                float mterm = par * expf(fminf(ml, 20.0f) + sl);
                out[(rbase + r) * 128 + u] = g1 * a1 + om * mterm;
            }
        }
    }
}

extern "C" void kernel_launch(void* const* d_in, const int* in_sizes, int n_in,
                              void* d_out, int out_size, void* d_ws, size_t ws_size,
                              hipStream_t stream) {
    const float* x     = (const float*)d_in[0];
    const float* w_hat = (const float*)d_in[1];
    const float* m_hat = (const float*)d_in[2];
    const float* whp   = (const float*)d_in[3];
    const float* mhp   = (const float*)d_in[4];
    const float* g     = (const float*)d_in[5];
    unsigned short* Bsw = (unsigned short*)d_ws;   // 4*16384*2 = 128 KiB
    float* outp = (float*)d_out;

    nalu_prep<<<64, 256, 0, stream>>>(w_hat, m_hat, whp, mhp, Bsw);
    nalu_main<<<256, 256, 0, stream>>>(x, Bsw, g, outp);
}